// Round 5
// baseline (696.438 us; speedup 1.0000x reference)
//
#include <hip/hip_runtime.h>
#include <hip/hip_bf16.h>
#include <hip/hip_fp16.h>

// SparseConvTranspose: gather-MFMA-scatter, round 5.
// Atomic-free global path: out rows partitioned into 1563 slices x 256 rows.
// One block owns a slice: all messages for it are accumulated in an fp32 LDS
// tile (LDS atomics), written once with plain stores. Fill pass builds
// per-(k,slice) lists with packed entries (in_row<<8 | local_row) so the main
// kernel reads NO maps. W pre-packed into per-MFMA-fragment bf16 layout.

using short8  = __attribute__((ext_vector_type(8))) short;
using floatx4 = __attribute__((ext_vector_type(4))) float;

constexpr int KOFF = 27;
constexpr int NIN  = 100000;
constexpr int NOUT = 400000;
constexpr int CIN  = 64;
constexpr int COUT = 32;
constexpr int MSGS = 100000;
constexpr int TILES = MSGS / 16;

constexpr int SL_ROWS  = 256;                 // out rows per slice (orow>>8)
constexpr int NS       = 1563;                // ceil(400000/256)
constexpr int CAP      = 128;                 // per-(k,slice) list cap (mean 64, sd 8)
constexpr int LDSTRIDE = 36;                  // fp32 words per LDS row (16B-aligned, bank-spread)

constexpr size_t FEATS_BYTES = (size_t)NIN * CIN * 2;            // 12.8 MB
constexpr size_t WPACK_BYTES = (size_t)KOFF * 2048 * 2;          // 110,592 B
constexpr size_t LISTS_BYTES = (size_t)KOFF * NS * CAP * 4;      // 21.6 MB
constexpr size_t GCNT_BYTES  = (size_t)KOFF * NS * 4;            // 168,804 B

constexpr size_t OFF_WPACK = FEATS_BYTES;
constexpr size_t OFF_LISTS = OFF_WPACK + ((WPACK_BYTES + 255) & ~(size_t)255);
constexpr size_t OFF_GCNT  = OFF_LISTS + ((LISTS_BYTES + 255) & ~(size_t)255);
constexpr size_t WS_NEED   = OFF_GCNT + GCNT_BYTES;              // ~34.8 MB

constexpr int CVT_BLOCKS   = (NIN * CIN / 8) / 256;              // 3125
constexpr int WPACK_BLOCKS = (KOFF * 2048) / 256;                // 216

__device__ __forceinline__ short f2bf(float f) {
    union { float f; unsigned u; } v; v.f = f;
    unsigned r = v.u + 0x7fff + ((v.u >> 16) & 1u);
    return (short)(r >> 16);
}

// ---------------- prep: feats f32->bf16 + W fragment pre-pack --------------
__global__ __launch_bounds__(256) void prep_kernel(
    const float* __restrict__ f, const float* __restrict__ weight,
    ushort* __restrict__ feats_bf, ushort* __restrict__ wpack)
{
    if (blockIdx.x < CVT_BLOCKS) {
        const int t = blockIdx.x * 256 + threadIdx.x;
        const float4* p = (const float4*)(f + (size_t)t * 8);
        float4 lo = p[0], hi = p[1];
        short8 v;
        v[0]=f2bf(lo.x); v[1]=f2bf(lo.y); v[2]=f2bf(lo.z); v[3]=f2bf(lo.w);
        v[4]=f2bf(hi.x); v[5]=f2bf(hi.y); v[6]=f2bf(hi.z); v[7]=f2bf(hi.w);
        *(short8*)(feats_bf + (size_t)t * 8) = v;
    } else {
        // i bits: k | sfrag | t | lane | j  (j low 3, lane 6, t 1, sfrag 1)
        const int i = (blockIdx.x - CVT_BLOCKS) * 256 + threadIdx.x;  // [0, 27*2048)
        const int j    = i & 7;
        const int lane = (i >> 3) & 63;
        const int t    = (i >> 9) & 1;
        const int sf   = (i >> 10) & 1;
        const int k    = i >> 11;
        const int row  = sf * 32 + (lane >> 4) * 8 + j;   // C_in index
        const int cl   = t * 16 + (lane & 15);            // C_out index
        wpack[i] = (ushort)f2bf(weight[(size_t)k * 2048 + row * 32 + cl]);
    }
}

// ---------------- fill: per-(k,slice) packed message lists -----------------
// grid (8, 27), 1024 threads; block handles 12500 msgs of one k.
__global__ __launch_bounds__(1024) void fill_kernel(
    const int* __restrict__ in_map,
    const int* __restrict__ out_map,
    int* __restrict__ lists,
    int* __restrict__ gcnt)
{
    const int k   = blockIdx.y;
    const int tid = threadIdx.x;
    const long long kM = (long long)k * MSGS;
    const int mbase = blockIdx.x * 12500;

    __shared__ int hist[NS];
    __shared__ int base[NS];
    for (int ss = tid; ss < NS; ss += 1024) hist[ss] = 0;
    __syncthreads();

    #pragma unroll 1
    for (int it = 0; it < 13; ++it) {
        const int ml = it * 1024 + tid;
        if (ml < 12500) {
            const int orow = out_map[kM + mbase + ml];
            atomicAdd(&hist[orow >> 8], 1);
        }
    }
    __syncthreads();
    for (int ss = tid; ss < NS; ss += 1024) {
        const int h = hist[ss];
        base[ss] = h ? atomicAdd(&gcnt[k * NS + ss], h) : 0;
        hist[ss] = 0;
    }
    __syncthreads();
    #pragma unroll 1
    for (int it = 0; it < 13; ++it) {
        const int ml = it * 1024 + tid;
        if (ml < 12500) {
            const long long m = kM + mbase + ml;
            const int orow = out_map[m];
            const int ss   = orow >> 8;
            const int pos  = base[ss] + atomicAdd(&hist[ss], 1);
            if (pos < CAP) {
                const int inr = in_map[m];
                lists[(size_t)(k * NS + ss) * CAP + pos] = (inr << 8) | (orow & 255);
            }
        }
    }
}

// ---------------- main: slice-owned LDS accumulation -----------------------
__global__ __launch_bounds__(512) void spconv_slice_kernel(
    const ushort* __restrict__ feats_bf,
    const ushort* __restrict__ wpack,
    const int*    __restrict__ lists,
    const int*    __restrict__ gcnt,
    float*        __restrict__ out)
{
    const int s    = blockIdx.x;                  // slice
    const int wave = threadIdx.x >> 6;            // 0..7
    const int lane = threadIdx.x & 63;
    const int col  = lane & 15;
    const int quad = lane >> 4;

    __shared__ float4 accv[SL_ROWS * LDSTRIDE / 4];   // 36,864 B
    float* acc = (float*)accv;
    for (int i = threadIdx.x; i < SL_ROWS * LDSTRIDE / 4; i += 512)
        accv[i] = make_float4(0.f, 0.f, 0.f, 0.f);
    __syncthreads();

    #pragma unroll 1
    for (int k = 0; k < KOFF; ++k) {
        const int bucket = k * NS + s;
        int c = gcnt[bucket];
        if (c > CAP) c = CAP;
        if (c <= 0) continue;
        const int nt = (c + 15) >> 4;
        int t = (wave + k) & 7;                   // rotate wave->tile map per k
        if (t >= nt) continue;

        // B fragments: 4 x b128 from prepacked layout
        const ushort* wp = wpack + (size_t)k * 2048;
        const short8 b00 = *(const short8*)(wp + (0 * 64 + lane) * 8);
        const short8 b01 = *(const short8*)(wp + (1 * 64 + lane) * 8);
        const short8 b10 = *(const short8*)(wp + (2 * 64 + lane) * 8);
        const short8 b11 = *(const short8*)(wp + (3 * 64 + lane) * 8);
        const int* list = lists + (size_t)bucket * CAP;

        #pragma unroll 1
        for (; t < nt; t += 8) {
            const int base = t * 16;

            int ec = base + col;
            const bool v = ec < c;
            if (!v) ec = c - 1;
            const int e   = list[ec];
            const int inr = e >> 8;

            const ushort* ar = feats_bf + (size_t)inr * CIN;
            short8 a0 = *(const short8*)(ar + quad * 8);
            short8 a1 = *(const short8*)(ar + 32 + quad * 8);
            if (!v) { a0 = (short8)0; a1 = (short8)0; }   // dummy lanes add 0

            int lrow[4];
            #pragma unroll
            for (int i = 0; i < 4; ++i) {
                int ee = base + quad * 4 + i;
                if (ee >= c) ee = c - 1;
                lrow[i] = list[ee] & 255;
            }

            floatx4 c0 = {0.f, 0.f, 0.f, 0.f};
            floatx4 c1 = {0.f, 0.f, 0.f, 0.f};
            c0 = __builtin_amdgcn_mfma_f32_16x16x32_bf16(a0, b00, c0, 0, 0, 0);
            c1 = __builtin_amdgcn_mfma_f32_16x16x32_bf16(a0, b01, c1, 0, 0, 0);
            c0 = __builtin_amdgcn_mfma_f32_16x16x32_bf16(a1, b10, c0, 0, 0, 0);
            c1 = __builtin_amdgcn_mfma_f32_16x16x32_bf16(a1, b11, c1, 0, 0, 0);

            #pragma unroll
            for (int i = 0; i < 4; ++i) {
                float* p = acc + lrow[i] * LDSTRIDE;
                atomicAdd(p + col,      c0[i]);
                atomicAdd(p + col + 16, c1[i]);
            }
        }
    }
    __syncthreads();

    // writeout: SL_ROWS x 32 f32, coalesced float4 stores
    const int rowbase = s * SL_ROWS;
    for (int idx = threadIdx.x; idx < SL_ROWS * 8; idx += 512) {
        const int r = idx >> 3, q = idx & 7;
        const int grow = rowbase + r;
        if (grow < NOUT) {
            const float4 vv = *(const float4*)(acc + r * LDSTRIDE + q * 4);
            *((float4*)(out + (size_t)grow * COUT) + q) = vv;
        }
    }
}

// ---------------- fallback (small ws): f32 atomics into d_out --------------
__global__ __launch_bounds__(256) void spconv_f32atomic_kernel(
    const float* __restrict__ feats,
    const float* __restrict__ weight,
    const int*   __restrict__ in_map,
    const int*   __restrict__ out_map,
    float*       __restrict__ out)
{
    const int k    = blockIdx.y;
    const int wave = threadIdx.x >> 6;
    const int lane = threadIdx.x & 63;
    const int col  = lane & 15;
    const int quad = lane >> 4;
    const int tile = blockIdx.x * 4 + wave;
    if (tile >= TILES) return;
    const int m0 = tile * 16;
    const long long mapbase = (long long)k * MSGS;

    const float* Wk = weight + k * (CIN * COUT);
    short8 bfr[2][2];
    #pragma unroll
    for (int ss = 0; ss < 2; ++ss)
        #pragma unroll
        for (int t = 0; t < 2; ++t)
            #pragma unroll
            for (int j = 0; j < 8; ++j)
                bfr[ss][t][j] = f2bf(Wk[(ss * 32 + quad * 8 + j) * COUT + t * 16 + col]);

    const int in_row = in_map[mapbase + m0 + col];
    const float* arow = feats + (long long)in_row * CIN + quad * 8;

    floatx4 c0 = {0.f, 0.f, 0.f, 0.f};
    floatx4 c1 = {0.f, 0.f, 0.f, 0.f};
    #pragma unroll
    for (int ss = 0; ss < 2; ++ss) {
        const float4* p = (const float4*)(arow + ss * 32);
        float4 lo = p[0], hi = p[1];
        short8 a;
        a[0]=f2bf(lo.x); a[1]=f2bf(lo.y); a[2]=f2bf(lo.z); a[3]=f2bf(lo.w);
        a[4]=f2bf(hi.x); a[5]=f2bf(hi.y); a[6]=f2bf(hi.z); a[7]=f2bf(hi.w);
        c0 = __builtin_amdgcn_mfma_f32_16x16x32_bf16(a, bfr[ss][0], c0, 0, 0, 0);
        c1 = __builtin_amdgcn_mfma_f32_16x16x32_bf16(a, bfr[ss][1], c1, 0, 0, 0);
    }
    #pragma unroll
    for (int i = 0; i < 4; ++i) {
        const int orow = out_map[mapbase + m0 + quad * 4 + i];
        float* po = out + (long long)orow * COUT;
        atomicAdd(po + col,      c0[i]);
        atomicAdd(po + col + 16, c1[i]);
    }
}

extern "C" void kernel_launch(void* const* d_in, const int* in_sizes, int n_in,
                              void* d_out, int out_size, void* d_ws, size_t ws_size,
                              hipStream_t stream) {
    const float* feats   = (const float*)d_in[0];
    const float* weight  = (const float*)d_in[1];
    const int*   in_map  = (const int*)d_in[2];
    const int*   out_map = (const int*)d_in[3];
    float*       out     = (float*)d_out;

    if (ws_size >= WS_NEED) {
        ushort* feats_bf = (ushort*)d_ws;
        ushort* wpack    = (ushort*)((char*)d_ws + OFF_WPACK);
        int*    lists    = (int*)((char*)d_ws + OFF_LISTS);
        int*    gcnt     = (int*)((char*)d_ws + OFF_GCNT);

        hipMemsetAsync(gcnt, 0, GCNT_BYTES, stream);
        prep_kernel<<<CVT_BLOCKS + WPACK_BLOCKS, 256, 0, stream>>>(
            feats, weight, feats_bf, wpack);
        fill_kernel<<<dim3(8, KOFF), 1024, 0, stream>>>(
            in_map, out_map, lists, gcnt);
        spconv_slice_kernel<<<NS, 512, 0, stream>>>(
            feats_bf, wpack, lists, gcnt, out);
    } else {
        hipMemsetAsync(d_out, 0, (size_t)out_size * sizeof(float), stream);
        spconv_f32atomic_kernel<<<dim3((TILES + 3) / 4, KOFF), 256, 0, stream>>>(
            feats, weight, in_map, out_map, out);
    }
}

// Round 6
// 349.357 us; speedup vs baseline: 1.9935x; 1.9935x over previous
//
#include <hip/hip_runtime.h>
#include <hip/hip_bf16.h>
#include <hip/hip_fp16.h>

// SparseConvTranspose round 6: two-phase, atomic-free accumulation.
// Walls measured: global atomics ~18G packets/s (r3/r4); LDS atomics ~4cyc/lane
// serial per CU (r5). So: phase C materializes all 2.7M messages (MFMA,
// streaming fp16 stores); phase D reduces per 256-row slice with exclusive
// wave-per-32-row-group ownership (plain LDS RMW, in-order per wave) and
// writes f32 out directly. Fill builds per-slice lists (entry = mid<<8|lrow).

using short8  = __attribute__((ext_vector_type(8))) short;
using floatx4 = __attribute__((ext_vector_type(4))) float;

constexpr int KOFF = 27;
constexpr int NIN  = 100000;
constexpr int NOUT = 400000;
constexpr int CIN  = 64;
constexpr int COUT = 32;
constexpr int MSGS = 100000;
constexpr int TOTAL_MSGS = KOFF * MSGS;        // 2,700,000
constexpr int TILES = MSGS / 16;               // 6250
constexpr int WPB   = 4;
constexpr int BLK_PER_K = 64;
constexpr int WSTRIDE = BLK_PER_K * WPB;       // 256 waves per k

constexpr int SL_ROWS = 256;                   // rows per slice
constexpr int NS      = (NOUT + SL_ROWS - 1) / SL_ROWS;   // 1563
constexpr int CAP_S   = 2048;                  // per-slice list cap (mean 1728, +7.7 sd)
constexpr int CAPG    = 384;                   // per-group cap (mean 216, +11 sd)

constexpr int FILL_BLOCKS = 512;
constexpr int MPB = (TOTAL_MSGS + FILL_BLOCKS - 1) / FILL_BLOCKS;  // 5274
constexpr int FILL_ITERS = (MPB + 1023) / 1024;                    // 6

// ---- tier-1 ws layout ----
constexpr size_t FEATS_BYTES  = (size_t)NIN * CIN * 2;             // 12.8 MB
constexpr size_t MSGS_BYTES   = (size_t)TOTAL_MSGS * COUT * 2;     // 172.8 MB
constexpr size_t SLISTS_BYTES = (size_t)NS * CAP_S * 4;            // 12.8 MB
constexpr size_t GCNT_BYTES   = 8192;
constexpr size_t OFF_MSGS   = FEATS_BYTES;
constexpr size_t OFF_SLISTS = OFF_MSGS + MSGS_BYTES;
constexpr size_t OFF_GCNT   = OFF_SLISTS + ((SLISTS_BYTES + 255) & ~(size_t)255);
constexpr size_t WS_NEED1   = OFF_GCNT + GCNT_BYTES;               // ~189.2 MiB

// ---- tier-2 (round-4 fallback) ws layout ----
constexpr size_t ACC_BYTES = (size_t)NOUT * COUT * 2;              // 25.6 MB
constexpr size_t WS_NEED2  = ACC_BYTES + FEATS_BYTES;              // 38.4 MB

constexpr int CVT_BLOCKS  = (NIN * CIN / 8) / 256;                 // 3125
constexpr int ZERO_BLOCKS = (int)(ACC_BYTES / 16) / 256;           // 6250

__device__ __forceinline__ short f2bf(float f) {
    union { float f; unsigned u; } v; v.f = f;
    unsigned r = v.u + 0x7fff + ((v.u >> 16) & 1u);
    return (short)(r >> 16);
}

// ================= prep (tier 1): feats f32 -> bf16 ========================
__global__ __launch_bounds__(256) void feats_cvt_kernel(
    const float* __restrict__ f, ushort* __restrict__ b)
{
    const int t = blockIdx.x * 256 + threadIdx.x;
    const float4* p = (const float4*)(f + (size_t)t * 8);
    float4 lo = p[0], hi = p[1];
    short8 v;
    v[0]=f2bf(lo.x); v[1]=f2bf(lo.y); v[2]=f2bf(lo.z); v[3]=f2bf(lo.w);
    v[4]=f2bf(hi.x); v[5]=f2bf(hi.y); v[6]=f2bf(hi.z); v[7]=f2bf(hi.w);
    *(short8*)(b + (size_t)t * 8) = v;
}

// ================= fill: per-slice message lists ===========================
// entry = (mid << 8) | lrow  (mid = flat message id < 2^22, lrow = orow & 255)
__global__ __launch_bounds__(1024) void fill_kernel(
    const int* __restrict__ out_map,
    int* __restrict__ slists,
    int* __restrict__ gcnt)
{
    const int tid  = threadIdx.x;
    const int base = blockIdx.x * MPB;

    __shared__ int hist[NS];
    __shared__ int hbase[NS];
    for (int ss = tid; ss < NS; ss += 1024) hist[ss] = 0;
    __syncthreads();

    #pragma unroll 1
    for (int it = 0; it < FILL_ITERS; ++it) {
        const int off = it * 1024 + tid;
        const int m = base + off;
        if (off < MPB && m < TOTAL_MSGS)
            atomicAdd(&hist[out_map[m] >> 8], 1);
    }
    __syncthreads();
    for (int ss = tid; ss < NS; ss += 1024) {
        const int h = hist[ss];
        hbase[ss] = h ? atomicAdd(&gcnt[ss], h) : 0;
        hist[ss] = 0;
    }
    __syncthreads();
    #pragma unroll 1
    for (int it = 0; it < FILL_ITERS; ++it) {
        const int off = it * 1024 + tid;
        const int m = base + off;
        if (off < MPB && m < TOTAL_MSGS) {
            const int orow = out_map[m];
            const int ss   = orow >> 8;
            const int pos  = hbase[ss] + atomicAdd(&hist[ss], 1);
            if (pos < CAP_S)
                slists[(size_t)ss * CAP_S + pos] = (m << 8) | (orow & 255);
        }
    }
}

// ================= phase C: message materialization (MFMA) =================
__global__ __launch_bounds__(256) void msgs_kernel(
    const ushort* __restrict__ feats_bf,
    const float*  __restrict__ weight,
    const int*    __restrict__ in_map,
    __half2*      __restrict__ msgs_h2)       // [TOTAL_MSGS * 16]
{
    const int k    = blockIdx.y;
    const int wave = threadIdx.x >> 6;
    const int lane = threadIdx.x & 63;
    const int col  = lane & 15;
    const int quad = lane >> 4;
    const long long kM = (long long)k * MSGS;

    // B frags: bfr[s][t][j] = W[k][s*32+quad*8+j][2*col+t]
    const float* Wk = weight + k * (CIN * COUT);
    short8 bfr[2][2];
    #pragma unroll
    for (int s = 0; s < 2; ++s)
        #pragma unroll
        for (int t = 0; t < 2; ++t)
            #pragma unroll
            for (int j = 0; j < 8; ++j)
                bfr[s][t][j] = f2bf(Wk[(s * 32 + quad * 8 + j) * COUT + 2 * col + t]);

    #define LOAD_INR(t, inr)                                          \
        {                                                             \
            const int tt = ((t) < TILES) ? (t) : (TILES - 1);         \
            inr = in_map[kM + (long long)tt * 16 + col];              \
        }
    #define LOAD_FEATS(inr, a0, a1)                                   \
        {                                                             \
            const ushort* ar = feats_bf + (long long)(inr) * CIN;     \
            a0 = *(const short8*)(ar + quad * 8);                     \
            a1 = *(const short8*)(ar + 32 + quad * 8);                \
        }

    const int t0 = blockIdx.x * WPB + wave;
    int inrA, inrB;
    LOAD_INR(t0, inrA);
    LOAD_INR(t0 + WSTRIDE, inrB);
    short8 a0A, a1A;
    LOAD_FEATS(inrA, a0A, a1A);

    for (int t = t0; t < TILES; t += WSTRIDE) {
        int inrC;
        LOAD_INR(t + 2 * WSTRIDE, inrC);
        short8 a0B, a1B;
        LOAD_FEATS(inrB, a0B, a1B);

        floatx4 c0 = {0.f, 0.f, 0.f, 0.f};
        floatx4 c1 = {0.f, 0.f, 0.f, 0.f};
        c0 = __builtin_amdgcn_mfma_f32_16x16x32_bf16(a0A, bfr[0][0], c0, 0, 0, 0);
        c1 = __builtin_amdgcn_mfma_f32_16x16x32_bf16(a0A, bfr[0][1], c1, 0, 0, 0);
        c0 = __builtin_amdgcn_mfma_f32_16x16x32_bf16(a1A, bfr[1][0], c0, 0, 0, 0);
        c1 = __builtin_amdgcn_mfma_f32_16x16x32_bf16(a1A, bfr[1][1], c1, 0, 0, 0);

        // stream out: tile t rows are messages kM + t*16 + (quad*4+i)
        const size_t mb = (size_t)(kM + (long long)t * 16);
        #pragma unroll
        for (int i = 0; i < 4; ++i)
            msgs_h2[(mb + quad * 4 + i) * 16 + col] = __floats2half2_rn(c0[i], c1[i]);

        inrA = inrB; a0A = a0B; a1A = a1B;
        inrB = inrC;
    }
    #undef LOAD_INR
    #undef LOAD_FEATS
}

// ================= phase D: slice-owned reduce =============================
__global__ __launch_bounds__(512) void reduce_kernel(
    const unsigned int* __restrict__ msgs_u32,   // [TOTAL_MSGS * 16] half2 as u32
    const int* __restrict__ slists,
    const int* __restrict__ gcnt,
    float* __restrict__ out)
{
    const int s    = blockIdx.x;
    const int tid  = threadIdx.x;
    const int wave = tid >> 6;
    const int lane = tid & 63;

    __shared__ float acc[SL_ROWS * COUT];        // 32 KB
    __shared__ int   binned[8 * CAPG];           // 12 KB
    __shared__ int   bcnt[8];

    {
        float4* av = (float4*)acc;
        for (int i = tid; i < SL_ROWS * COUT / 4; i += 512)
            av[i] = make_float4(0.f, 0.f, 0.f, 0.f);
        if (tid < 8) bcnt[tid] = 0;
    }
    __syncthreads();

    const int cnt_s = min(gcnt[s], CAP_S);
    const int* sl = slists + (size_t)s * CAP_S;

    // ---- ballot-bin entries by 32-row group g = (lrow>>5) ----
    for (int idx = tid; idx < cnt_s; idx += 512) {
        const int e = sl[idx];
        const int g = (e >> 5) & 7;
        #pragma unroll
        for (int gi = 0; gi < 8; ++gi) {
            const unsigned long long m = __ballot(g == gi);
            if (m == 0) continue;
            const int leader = __ffsll((unsigned long long)m) - 1;
            int base = 0;
            if (lane == leader) base = atomicAdd(&bcnt[gi], __popcll(m));
            base = __shfl(base, leader);
            if (g == gi) {
                const int pos = base + __popcll(m & ((1ull << lane) - 1));
                if (pos < CAPG) binned[gi * CAPG + pos] = e;
            }
        }
    }
    __syncthreads();

    // ---- walk: wave owns group `wave` (rows [wave*32, wave*32+32)) ----
    {
        const int g   = wave;
        const int cnt = min(bcnt[g], CAPG);
        const int* bg = binned + g * CAPG;
        const int sub = lane >> 4;               // entry slot 0..3
        const int cl  = lane & 15;               // dword (half2) within msg

        int  e1 = -1, e2 = -1;
        unsigned int u1 = 0, u2 = 0;
        if (sub < cnt)     e1 = bg[sub];
        if (4 + sub < cnt) e2 = bg[4 + sub];
        if (e1 >= 0) u1 = msgs_u32[(size_t)(e1 >> 8) * 16 + cl];
        if (e2 >= 0) u2 = msgs_u32[(size_t)(e2 >> 8) * 16 + cl];

        #pragma unroll 1
        for (int i = 0; i < cnt; i += 4) {
            int e3 = -1; unsigned int u3 = 0;
            if (i + 8 + sub < cnt) e3 = bg[i + 8 + sub];
            if (e3 >= 0) u3 = msgs_u32[(size_t)(e3 >> 8) * 16 + cl];

            // 4 masked sub-steps; same-wave DS ordering makes same-row safe
            #pragma unroll
            for (int j = 0; j < 4; ++j) {
                if (sub == j && e1 >= 0) {
                    const int lr = e1 & 255;
                    const float2 f = __half22float2(*(const __half2*)&u1);
                    float2* p = (float2*)(acc + lr * COUT + cl * 2);
                    float2 d = *p;
                    d.x += f.x; d.y += f.y;
                    *p = d;
                }
            }
            e1 = e2; u1 = u2; e2 = e3; u2 = u3;
        }
    }
    __syncthreads();

    // ---- writeout: plain coalesced f32 stores ----
    const int rowbase = s * SL_ROWS;
    const int rows = min(SL_ROWS, NOUT - rowbase);
    for (int idx = tid; idx < rows * 8; idx += 512) {
        const int r = idx >> 3, q = idx & 7;
        *((float4*)(out + (size_t)(rowbase + r) * COUT) + q) =
            *(const float4*)(acc + r * COUT + q * 4);
    }
}

// ================= tier-2 fallback: round-4 path ===========================
__global__ __launch_bounds__(256) void prep4_kernel(
    const float* __restrict__ f, ushort* __restrict__ b, float4* __restrict__ accz)
{
    if (blockIdx.x < CVT_BLOCKS) {
        const int t = blockIdx.x * 256 + threadIdx.x;
        const float4* p = (const float4*)(f + (size_t)t * 8);
        float4 lo = p[0], hi = p[1];
        short8 v;
        v[0]=f2bf(lo.x); v[1]=f2bf(lo.y); v[2]=f2bf(lo.z); v[3]=f2bf(lo.w);
        v[4]=f2bf(hi.x); v[5]=f2bf(hi.y); v[6]=f2bf(hi.z); v[7]=f2bf(hi.w);
        *(short8*)(b + (size_t)t * 8) = v;
    } else {
        const int t = (blockIdx.x - CVT_BLOCKS) * 256 + threadIdx.x;
        accz[t] = make_float4(0.f, 0.f, 0.f, 0.f);
    }
}

__global__ __launch_bounds__(256) void spconv_pipe_kernel(
    const ushort* __restrict__ feats_bf,
    const float*  __restrict__ weight,
    const int*    __restrict__ in_map,
    const int*    __restrict__ out_map,
    __half2*      __restrict__ accum)
{
    const int k    = blockIdx.y;
    const int wave = threadIdx.x >> 6;
    const int lane = threadIdx.x & 63;
    const int col  = lane & 15;
    const int quad = lane >> 4;
    const long long kM = (long long)k * MSGS;

    const float* Wk = weight + k * (CIN * COUT);
    short8 bfr[2][2];
    #pragma unroll
    for (int s = 0; s < 2; ++s)
        #pragma unroll
        for (int t = 0; t < 2; ++t)
            #pragma unroll
            for (int j = 0; j < 8; ++j)
                bfr[s][t][j] = f2bf(Wk[(s * 32 + quad * 8 + j) * COUT + 2 * col + t]);

    #define LOAD_MAPS(t, inr, orow)                                   \
        {                                                             \
            const int tt = ((t) < TILES) ? (t) : (TILES - 1);         \
            const long long mb = kM + (long long)tt * 16;             \
            inr = in_map[mb + col];                                   \
            _Pragma("unroll")                                         \
            for (int i = 0; i < 4; ++i) orow[i] = out_map[mb + quad * 4 + i]; \
        }
    #define LOAD_FEATS(inr, a0, a1)                                   \
        {                                                             \
            const ushort* ar = feats_bf + (long long)(inr) * CIN;     \
            a0 = *(const short8*)(ar + quad * 8);                     \
            a1 = *(const short8*)(ar + 32 + quad * 8);                \
        }

    const int t0 = blockIdx.x * WPB + wave;
    int inrA, orowA[4];  LOAD_MAPS(t0,           inrA, orowA);
    int inrB, orowB[4];  LOAD_MAPS(t0 + WSTRIDE, inrB, orowB);
    short8 a0A, a1A;     LOAD_FEATS(inrA, a0A, a1A);

    for (int t = t0; t < TILES; t += WSTRIDE) {
        int inrC, orowC[4];
        LOAD_MAPS(t + 2 * WSTRIDE, inrC, orowC);
        short8 a0B, a1B;
        LOAD_FEATS(inrB, a0B, a1B);

        floatx4 c0 = {0.f, 0.f, 0.f, 0.f};
        floatx4 c1 = {0.f, 0.f, 0.f, 0.f};
        c0 = __builtin_amdgcn_mfma_f32_16x16x32_bf16(a0A, bfr[0][0], c0, 0, 0, 0);
        c1 = __builtin_amdgcn_mfma_f32_16x16x32_bf16(a0A, bfr[0][1], c1, 0, 0, 0);
        c0 = __builtin_amdgcn_mfma_f32_16x16x32_bf16(a1A, bfr[1][0], c0, 0, 0, 0);
        c1 = __builtin_amdgcn_mfma_f32_16x16x32_bf16(a1A, bfr[1][1], c1, 0, 0, 0);

        #pragma unroll
        for (int i = 0; i < 4; ++i) {
            __half2 h = __floats2half2_rn(c0[i], c1[i]);
            unsafeAtomicAdd(accum + (long long)orowA[i] * 16 + col, h);
        }
        inrA = inrB; a0A = a0B; a1A = a1B;
        inrB = inrC;
        #pragma unroll
        for (int i = 0; i < 4; ++i) { orowA[i] = orowB[i]; orowB[i] = orowC[i]; }
    }
    #undef LOAD_MAPS
    #undef LOAD_FEATS
}

__global__ __launch_bounds__(256) void h2_to_f32_kernel(
    const __half2* __restrict__ acc, float* __restrict__ out)
{
    const int t = blockIdx.x * blockDim.x + threadIdx.x;
    const __half2* p = acc + (size_t)t * 4;
    float2 f0 = __half22float2(p[0]);
    float2 f1 = __half22float2(p[1]);
    float2 f2 = __half22float2(p[2]);
    float2 f3 = __half22float2(p[3]);
    float4* o = (float4*)out + (size_t)t * 2;
    o[0] = make_float4(f0.x, f0.y, f1.x, f1.y);
    o[1] = make_float4(f2.x, f2.y, f3.x, f3.y);
}

// ================= tier-3 last resort: f32 atomics =========================
__global__ __launch_bounds__(256) void spconv_f32atomic_kernel(
    const float* __restrict__ feats,
    const float* __restrict__ weight,
    const int*   __restrict__ in_map,
    const int*   __restrict__ out_map,
    float*       __restrict__ out)
{
    const int k    = blockIdx.y;
    const int wave = threadIdx.x >> 6;
    const int lane = threadIdx.x & 63;
    const int col  = lane & 15;
    const int quad = lane >> 4;
    const int tile = blockIdx.x * WPB + wave;
    if (tile >= TILES) return;
    const int m0 = tile * 16;
    const long long mapbase = (long long)k * MSGS;

    const float* Wk = weight + k * (CIN * COUT);
    short8 bfr[2][2];
    #pragma unroll
    for (int ss = 0; ss < 2; ++ss)
        #pragma unroll
        for (int t = 0; t < 2; ++t)
            #pragma unroll
            for (int j = 0; j < 8; ++j)
                bfr[ss][t][j] = f2bf(Wk[(ss * 32 + quad * 8 + j) * COUT + t * 16 + col]);

    const int in_row = in_map[mapbase + m0 + col];
    const float* arow = feats + (long long)in_row * CIN + quad * 8;

    floatx4 c0 = {0.f, 0.f, 0.f, 0.f};
    floatx4 c1 = {0.f, 0.f, 0.f, 0.f};
    #pragma unroll
    for (int ss = 0; ss < 2; ++ss) {
        const float4* p = (const float4*)(arow + ss * 32);
        float4 lo = p[0], hi = p[1];
        short8 a;
        a[0]=f2bf(lo.x); a[1]=f2bf(lo.y); a[2]=f2bf(lo.z); a[3]=f2bf(lo.w);
        a[4]=f2bf(hi.x); a[5]=f2bf(hi.y); a[6]=f2bf(hi.z); a[7]=f2bf(hi.w);
        c0 = __builtin_amdgcn_mfma_f32_16x16x32_bf16(a, bfr[ss][0], c0, 0, 0, 0);
        c1 = __builtin_amdgcn_mfma_f32_16x16x32_bf16(a, bfr[ss][1], c1, 0, 0, 0);
    }
    #pragma unroll
    for (int i = 0; i < 4; ++i) {
        const int orow = out_map[mapbase + m0 + quad * 4 + i];
        float* po = out + (long long)orow * COUT;
        atomicAdd(po + col,      c0[i]);
        atomicAdd(po + col + 16, c1[i]);
    }
}

extern "C" void kernel_launch(void* const* d_in, const int* in_sizes, int n_in,
                              void* d_out, int out_size, void* d_ws, size_t ws_size,
                              hipStream_t stream) {
    const float* feats   = (const float*)d_in[0];
    const float* weight  = (const float*)d_in[1];
    const int*   in_map  = (const int*)d_in[2];
    const int*   out_map = (const int*)d_in[3];
    float*       out     = (float*)d_out;

    if (ws_size >= WS_NEED1) {
        ushort*       feats_bf = (ushort*)d_ws;
        __half2*      msgs     = (__half2*)((char*)d_ws + OFF_MSGS);
        int*          slists   = (int*)((char*)d_ws + OFF_SLISTS);
        int*          gcnt     = (int*)((char*)d_ws + OFF_GCNT);

        hipMemsetAsync(gcnt, 0, GCNT_BYTES, stream);
        feats_cvt_kernel<<<CVT_BLOCKS, 256, 0, stream>>>(feats, feats_bf);
        fill_kernel<<<FILL_BLOCKS, 1024, 0, stream>>>(out_map, slists, gcnt);
        msgs_kernel<<<dim3(BLK_PER_K, KOFF), 256, 0, stream>>>(
            feats_bf, weight, in_map, msgs);
        reduce_kernel<<<NS, 512, 0, stream>>>(
            (const unsigned int*)msgs, slists, gcnt, out);
    } else if (ws_size >= WS_NEED2) {
        __half2* accum    = (__half2*)d_ws;
        ushort*  feats_bf = (ushort*)((char*)d_ws + ACC_BYTES);
        prep4_kernel<<<CVT_BLOCKS + ZERO_BLOCKS, 256, 0, stream>>>(
            feats, feats_bf, (float4*)accum);
        spconv_pipe_kernel<<<dim3(BLK_PER_K, KOFF), 256, 0, stream>>>(
            feats_bf, weight, in_map, out_map, accum);
        h2_to_f32_kernel<<<(NOUT * 16 / 4) / 256, 256, 0, stream>>>(accum, out);
    } else {
        hipMemsetAsync(d_out, 0, (size_t)out_size * sizeof(float), stream);
        spconv_f32atomic_kernel<<<dim3((TILES + WPB - 1) / WPB, KOFF), 256, 0, stream>>>(
            feats, weight, in_map, out_map, out);
    }
}

// Round 7
// 289.646 us; speedup vs baseline: 2.4044x; 1.2062x over previous
//
#include <hip/hip_runtime.h>
#include <hip/hip_bf16.h>
#include <hip/hip_fp16.h>

// SparseConvTranspose round 7: two-phase, atomic-free accumulation.
// Phase C: MFMA message materialization (unchanged from r6).
// Phase D v2: per-slice LDS counting-sort by local row, then register-only
// accumulation -- each 16-lane quad owns 8 contiguous rows, walks its sorted
// entry range in chunks of 16 with all gather loads in flight, writes f32
// out directly (no LDS RMW at all). r5 lesson: LDS atomics are ~4cyc/lane
// serialized per CU, so they're used only for the O(cnt) sort, not O(cnt*32).

using short8  = __attribute__((ext_vector_type(8))) short;
using floatx4 = __attribute__((ext_vector_type(4))) float;

constexpr int KOFF = 27;
constexpr int NIN  = 100000;
constexpr int NOUT = 400000;
constexpr int CIN  = 64;
constexpr int COUT = 32;
constexpr int MSGS = 100000;
constexpr int TOTAL_MSGS = KOFF * MSGS;        // 2,700,000
constexpr int TILES = MSGS / 16;               // 6250
constexpr int WPB   = 4;
constexpr int BLK_PER_K = 64;
constexpr int WSTRIDE = BLK_PER_K * WPB;       // 256 waves per k

constexpr int SL_ROWS = 256;                   // rows per slice
constexpr int NS      = (NOUT + SL_ROWS - 1) / SL_ROWS;   // 1563
constexpr int CAP_S   = 2048;                  // per-slice list cap (mean 1728, +7.7 sd)

constexpr int FILL_BLOCKS = 512;
constexpr int MPB = (TOTAL_MSGS + FILL_BLOCKS - 1) / FILL_BLOCKS;  // 5274
constexpr int FILL_ITERS = (MPB + 1023) / 1024;                    // 6

// ---- tier-1 ws layout ----
constexpr size_t FEATS_BYTES  = (size_t)NIN * CIN * 2;             // 12.8 MB
constexpr size_t MSGS_BYTES   = (size_t)TOTAL_MSGS * COUT * 2;     // 172.8 MB
constexpr size_t SLISTS_BYTES = (size_t)NS * CAP_S * 4;            // 12.8 MB
constexpr size_t GCNT_BYTES   = 8192;
constexpr size_t OFF_MSGS   = FEATS_BYTES;
constexpr size_t OFF_SLISTS = OFF_MSGS + MSGS_BYTES;
constexpr size_t OFF_GCNT   = OFF_SLISTS + ((SLISTS_BYTES + 255) & ~(size_t)255);
constexpr size_t WS_NEED1   = OFF_GCNT + GCNT_BYTES;               // ~189.2 MiB

// ---- tier-2 (round-4 fallback) ws layout ----
constexpr size_t ACC_BYTES = (size_t)NOUT * COUT * 2;              // 25.6 MB
constexpr size_t WS_NEED2  = ACC_BYTES + FEATS_BYTES;              // 38.4 MB

constexpr int CVT_BLOCKS  = (NIN * CIN / 8) / 256;                 // 3125
constexpr int ZERO_BLOCKS = (int)(ACC_BYTES / 16) / 256;           // 6250

__device__ __forceinline__ short f2bf(float f) {
    union { float f; unsigned u; } v; v.f = f;
    unsigned r = v.u + 0x7fff + ((v.u >> 16) & 1u);
    return (short)(r >> 16);
}

// ================= prep (tier 1): feats f32 -> bf16 ========================
__global__ __launch_bounds__(256) void feats_cvt_kernel(
    const float* __restrict__ f, ushort* __restrict__ b)
{
    const int t = blockIdx.x * 256 + threadIdx.x;
    const float4* p = (const float4*)(f + (size_t)t * 8);
    float4 lo = p[0], hi = p[1];
    short8 v;
    v[0]=f2bf(lo.x); v[1]=f2bf(lo.y); v[2]=f2bf(lo.z); v[3]=f2bf(lo.w);
    v[4]=f2bf(hi.x); v[5]=f2bf(hi.y); v[6]=f2bf(hi.z); v[7]=f2bf(hi.w);
    *(short8*)(b + (size_t)t * 8) = v;
}

// ================= fill: per-slice message lists ===========================
// entry = (mid << 8) | lrow  (mid = flat message id < 2^22, lrow = orow & 255)
__global__ __launch_bounds__(1024) void fill_kernel(
    const int* __restrict__ out_map,
    int* __restrict__ slists,
    int* __restrict__ gcnt)
{
    const int tid  = threadIdx.x;
    const int base = blockIdx.x * MPB;

    __shared__ int hist[NS];
    __shared__ int hbase[NS];
    for (int ss = tid; ss < NS; ss += 1024) hist[ss] = 0;
    __syncthreads();

    #pragma unroll 1
    for (int it = 0; it < FILL_ITERS; ++it) {
        const int off = it * 1024 + tid;
        const int m = base + off;
        if (off < MPB && m < TOTAL_MSGS)
            atomicAdd(&hist[out_map[m] >> 8], 1);
    }
    __syncthreads();
    for (int ss = tid; ss < NS; ss += 1024) {
        const int h = hist[ss];
        hbase[ss] = h ? atomicAdd(&gcnt[ss], h) : 0;
        hist[ss] = 0;
    }
    __syncthreads();
    #pragma unroll 1
    for (int it = 0; it < FILL_ITERS; ++it) {
        const int off = it * 1024 + tid;
        const int m = base + off;
        if (off < MPB && m < TOTAL_MSGS) {
            const int orow = out_map[m];
            const int ss   = orow >> 8;
            const int pos  = hbase[ss] + atomicAdd(&hist[ss], 1);
            if (pos < CAP_S)
                slists[(size_t)ss * CAP_S + pos] = (m << 8) | (orow & 255);
        }
    }
}

// ================= phase C: message materialization (MFMA) =================
__global__ __launch_bounds__(256) void msgs_kernel(
    const ushort* __restrict__ feats_bf,
    const float*  __restrict__ weight,
    const int*    __restrict__ in_map,
    __half2*      __restrict__ msgs_h2)       // [TOTAL_MSGS * 16]
{
    const int k    = blockIdx.y;
    const int wave = threadIdx.x >> 6;
    const int lane = threadIdx.x & 63;
    const int col  = lane & 15;
    const int quad = lane >> 4;
    const long long kM = (long long)k * MSGS;

    // B frags: bfr[s][t][j] = W[k][s*32+quad*8+j][2*col+t]
    const float* Wk = weight + k * (CIN * COUT);
    short8 bfr[2][2];
    #pragma unroll
    for (int s = 0; s < 2; ++s)
        #pragma unroll
        for (int t = 0; t < 2; ++t)
            #pragma unroll
            for (int j = 0; j < 8; ++j)
                bfr[s][t][j] = f2bf(Wk[(s * 32 + quad * 8 + j) * COUT + 2 * col + t]);

    #define LOAD_INR(t, inr)                                          \
        {                                                             \
            const int tt = ((t) < TILES) ? (t) : (TILES - 1);         \
            inr = in_map[kM + (long long)tt * 16 + col];              \
        }
    #define LOAD_FEATS(inr, a0, a1)                                   \
        {                                                             \
            const ushort* ar = feats_bf + (long long)(inr) * CIN;     \
            a0 = *(const short8*)(ar + quad * 8);                     \
            a1 = *(const short8*)(ar + 32 + quad * 8);                \
        }

    const int t0 = blockIdx.x * WPB + wave;
    int inrA, inrB;
    LOAD_INR(t0, inrA);
    LOAD_INR(t0 + WSTRIDE, inrB);
    short8 a0A, a1A;
    LOAD_FEATS(inrA, a0A, a1A);

    for (int t = t0; t < TILES; t += WSTRIDE) {
        int inrC;
        LOAD_INR(t + 2 * WSTRIDE, inrC);
        short8 a0B, a1B;
        LOAD_FEATS(inrB, a0B, a1B);

        floatx4 c0 = {0.f, 0.f, 0.f, 0.f};
        floatx4 c1 = {0.f, 0.f, 0.f, 0.f};
        c0 = __builtin_amdgcn_mfma_f32_16x16x32_bf16(a0A, bfr[0][0], c0, 0, 0, 0);
        c1 = __builtin_amdgcn_mfma_f32_16x16x32_bf16(a0A, bfr[0][1], c1, 0, 0, 0);
        c0 = __builtin_amdgcn_mfma_f32_16x16x32_bf16(a1A, bfr[1][0], c0, 0, 0, 0);
        c1 = __builtin_amdgcn_mfma_f32_16x16x32_bf16(a1A, bfr[1][1], c1, 0, 0, 0);

        const size_t mb = (size_t)(kM + (long long)t * 16);
        #pragma unroll
        for (int i = 0; i < 4; ++i)
            msgs_h2[(mb + quad * 4 + i) * 16 + col] = __floats2half2_rn(c0[i], c1[i]);

        inrA = inrB; a0A = a0B; a1A = a1B;
        inrB = inrC;
    }
    #undef LOAD_INR
    #undef LOAD_FEATS
}

// ================= phase D v2: counting-sort + register reduce =============
__global__ __launch_bounds__(512) void reduce_kernel(
    const unsigned int* __restrict__ msgs_u32,   // [TOTAL_MSGS * 16] half2 as u32
    const int* __restrict__ slists,
    const int* __restrict__ gcnt,
    float* __restrict__ out)
{
    const int s    = blockIdx.x;
    const int tid  = threadIdx.x;
    const int lane = tid & 63;
    const int qq   = tid >> 4;                   // 0..31 quad id in block
    const int cl   = tid & 15;                   // half2 slot within message
    const int qbase = lane & 48;                 // quad base lane within wave

    __shared__ int sh_ent[CAP_S];                // 8 KB  staged entries
    __shared__ int sorted_s[CAP_S + 16];         // 8 KB+ sorted mids (padded)
    __shared__ int hist[SL_ROWS];                // 1 KB
    __shared__ int start_s[SL_ROWS];             // 1 KB  row start (fixed)
    __shared__ int cur_s[SL_ROWS];               // 1 KB  cursor -> row end

    for (int i = tid; i < SL_ROWS; i += 512) hist[i] = 0;
    __syncthreads();

    const int cnt = min(gcnt[s], CAP_S);

    // ---- stage + histogram ----
    for (int idx = tid; idx < cnt; idx += 512) {
        const int e = slists[(size_t)s * CAP_S + idx];
        sh_ent[idx] = e;
        atomicAdd(&hist[e & 255], 1);
    }
    __syncthreads();

    // ---- exclusive scan over 256 bins (wave 0) ----
    if (tid < 64) {
        const int b = tid * 4;
        const int h0 = hist[b], h1 = hist[b + 1], h2 = hist[b + 2], h3 = hist[b + 3];
        const int own = h0 + h1 + h2 + h3;
        int t = own;
        #pragma unroll
        for (int d = 1; d < 64; d <<= 1) {
            const int n = __shfl_up(t, d);
            if (tid >= (unsigned)d) t += n;
        }
        const int base = t - own;
        start_s[b]     = base;
        start_s[b + 1] = base + h0;
        start_s[b + 2] = base + h0 + h1;
        start_s[b + 3] = base + h0 + h1 + h2;
        cur_s[b]       = base;
        cur_s[b + 1]   = base + h0;
        cur_s[b + 2]   = base + h0 + h1;
        cur_s[b + 3]   = base + h0 + h1 + h2;
    }
    __syncthreads();

    // ---- scatter into sorted order (cur_s[r] becomes row end) ----
    for (int idx = tid; idx < cnt; idx += 512) {
        const int e = sh_ent[idx];
        const int pos = atomicAdd(&cur_s[e & 255], 1);
        sorted_s[pos] = e >> 8;                  // mid only
    }
    __syncthreads();

    // ---- register-only walk: quad qq owns rows [qq*8, qq*8+8) ----
    const int rowbase = s * SL_ROWS;
    const int rows = min(SL_ROWS, NOUT - rowbase);
    const int r0   = qq * 8;
    const int rend = min(r0 + 8, rows);

    if (r0 < rows) {
        float2 acc = make_float2(0.f, 0.f);
        int r = r0;
        const int start0 = start_s[r0];
        const int endAll = cur_s[rend - 1];
        int e = cur_s[r];

        for (int cb = start0; cb < endAll; cb += 16) {
            const int mload = sorted_s[cb + cl];         // padded over-read ok
            unsigned int uu[16];
            #pragma unroll
            for (int j = 0; j < 16; ++j) {
                const int mids = __shfl(mload, qbase + j);
                const int mid  = (cb + j < endAll) ? mids : 0;
                uu[j] = msgs_u32[(size_t)mid * 16 + cl]; // 16 loads in flight
            }
            #pragma unroll
            for (int j = 0; j < 16; ++j) {
                const int gidx = cb + j;
                if (gidx < endAll) {
                    while (gidx >= e) {                  // flush completed row(s)
                        *(float2*)(out + (size_t)(rowbase + r) * COUT + cl * 2) = acc;
                        acc = make_float2(0.f, 0.f);
                        ++r;
                        e = cur_s[r];
                    }
                    const float2 f = __half22float2(*(const __half2*)&uu[j]);
                    acc.x += f.x; acc.y += f.y;
                }
            }
        }
        // flush last active row + trailing empty rows
        for (; r < rend; ++r) {
            *(float2*)(out + (size_t)(rowbase + r) * COUT + cl * 2) = acc;
            acc = make_float2(0.f, 0.f);
        }
    }
}

// ================= tier-2 fallback: round-4 path ===========================
__global__ __launch_bounds__(256) void prep4_kernel(
    const float* __restrict__ f, ushort* __restrict__ b, float4* __restrict__ accz)
{
    if (blockIdx.x < CVT_BLOCKS) {
        const int t = blockIdx.x * 256 + threadIdx.x;
        const float4* p = (const float4*)(f + (size_t)t * 8);
        float4 lo = p[0], hi = p[1];
        short8 v;
        v[0]=f2bf(lo.x); v[1]=f2bf(lo.y); v[2]=f2bf(lo.z); v[3]=f2bf(lo.w);
        v[4]=f2bf(hi.x); v[5]=f2bf(hi.y); v[6]=f2bf(hi.z); v[7]=f2bf(hi.w);
        *(short8*)(b + (size_t)t * 8) = v;
    } else {
        const int t = (blockIdx.x - CVT_BLOCKS) * 256 + threadIdx.x;
        accz[t] = make_float4(0.f, 0.f, 0.f, 0.f);
    }
}

__global__ __launch_bounds__(256) void spconv_pipe_kernel(
    const ushort* __restrict__ feats_bf,
    const float*  __restrict__ weight,
    const int*    __restrict__ in_map,
    const int*    __restrict__ out_map,
    __half2*      __restrict__ accum)
{
    const int k    = blockIdx.y;
    const int wave = threadIdx.x >> 6;
    const int lane = threadIdx.x & 63;
    const int col  = lane & 15;
    const int quad = lane >> 4;
    const long long kM = (long long)k * MSGS;

    const float* Wk = weight + k * (CIN * COUT);
    short8 bfr[2][2];
    #pragma unroll
    for (int s = 0; s < 2; ++s)
        #pragma unroll
        for (int t = 0; t < 2; ++t)
            #pragma unroll
            for (int j = 0; j < 8; ++j)
                bfr[s][t][j] = f2bf(Wk[(s * 32 + quad * 8 + j) * COUT + 2 * col + t]);

    #define LOAD_MAPS(t, inr, orow)                                   \
        {                                                             \
            const int tt = ((t) < TILES) ? (t) : (TILES - 1);         \
            const long long mb = kM + (long long)tt * 16;             \
            inr = in_map[mb + col];                                   \
            _Pragma("unroll")                                         \
            for (int i = 0; i < 4; ++i) orow[i] = out_map[mb + quad * 4 + i]; \
        }
    #define LOAD_FEATS(inr, a0, a1)                                   \
        {                                                             \
            const ushort* ar = feats_bf + (long long)(inr) * CIN;     \
            a0 = *(const short8*)(ar + quad * 8);                     \
            a1 = *(const short8*)(ar + 32 + quad * 8);                \
        }

    const int t0 = blockIdx.x * WPB + wave;
    int inrA, orowA[4];  LOAD_MAPS(t0,           inrA, orowA);
    int inrB, orowB[4];  LOAD_MAPS(t0 + WSTRIDE, inrB, orowB);
    short8 a0A, a1A;     LOAD_FEATS(inrA, a0A, a1A);

    for (int t = t0; t < TILES; t += WSTRIDE) {
        int inrC, orowC[4];
        LOAD_MAPS(t + 2 * WSTRIDE, inrC, orowC);
        short8 a0B, a1B;
        LOAD_FEATS(inrB, a0B, a1B);

        floatx4 c0 = {0.f, 0.f, 0.f, 0.f};
        floatx4 c1 = {0.f, 0.f, 0.f, 0.f};
        c0 = __builtin_amdgcn_mfma_f32_16x16x32_bf16(a0A, bfr[0][0], c0, 0, 0, 0);
        c1 = __builtin_amdgcn_mfma_f32_16x16x32_bf16(a0A, bfr[0][1], c1, 0, 0, 0);
        c0 = __builtin_amdgcn_mfma_f32_16x16x32_bf16(a1A, bfr[1][0], c0, 0, 0, 0);
        c1 = __builtin_amdgcn_mfma_f32_16x16x32_bf16(a1A, bfr[1][1], c1, 0, 0, 0);

        #pragma unroll
        for (int i = 0; i < 4; ++i) {
            __half2 h = __floats2half2_rn(c0[i], c1[i]);
            unsafeAtomicAdd(accum + (long long)orowA[i] * 16 + col, h);
        }
        inrA = inrB; a0A = a0B; a1A = a1B;
        inrB = inrC;
        #pragma unroll
        for (int i = 0; i < 4; ++i) { orowA[i] = orowB[i]; orowB[i] = orowC[i]; }
    }
    #undef LOAD_MAPS
    #undef LOAD_FEATS
}

__global__ __launch_bounds__(256) void h2_to_f32_kernel(
    const __half2* __restrict__ acc, float* __restrict__ out)
{
    const int t = blockIdx.x * blockDim.x + threadIdx.x;
    const __half2* p = acc + (size_t)t * 4;
    float2 f0 = __half22float2(p[0]);
    float2 f1 = __half22float2(p[1]);
    float2 f2 = __half22float2(p[2]);
    float2 f3 = __half22float2(p[3]);
    float4* o = (float4*)out + (size_t)t * 2;
    o[0] = make_float4(f0.x, f0.y, f1.x, f1.y);
    o[1] = make_float4(f2.x, f2.y, f3.x, f3.y);
}

// ================= tier-3 last resort: f32 atomics =========================
__global__ __launch_bounds__(256) void spconv_f32atomic_kernel(
    const float* __restrict__ feats,
    const float* __restrict__ weight,
    const int*   __restrict__ in_map,
    const int*   __restrict__ out_map,
    float*       __restrict__ out)
{
    const int k    = blockIdx.y;
    const int wave = threadIdx.x >> 6;
    const int lane = threadIdx.x & 63;
    const int col  = lane & 15;
    const int quad = lane >> 4;
    const int tile = blockIdx.x * WPB + wave;
    if (tile >= TILES) return;
    const int m0 = tile * 16;
    const long long mapbase = (long long)k * MSGS;

    const float* Wk = weight + k * (CIN * COUT);
    short8 bfr[2][2];
    #pragma unroll
    for (int ss = 0; ss < 2; ++ss)
        #pragma unroll
        for (int t = 0; t < 2; ++t)
            #pragma unroll
            for (int j = 0; j < 8; ++j)
                bfr[ss][t][j] = f2bf(Wk[(ss * 32 + quad * 8 + j) * COUT + t * 16 + col]);

    const int in_row = in_map[mapbase + m0 + col];
    const float* arow = feats + (long long)in_row * CIN + quad * 8;

    floatx4 c0 = {0.f, 0.f, 0.f, 0.f};
    floatx4 c1 = {0.f, 0.f, 0.f, 0.f};
    #pragma unroll
    for (int ss = 0; ss < 2; ++ss) {
        const float4* p = (const float4*)(arow + ss * 32);
        float4 lo = p[0], hi = p[1];
        short8 a;
        a[0]=f2bf(lo.x); a[1]=f2bf(lo.y); a[2]=f2bf(lo.z); a[3]=f2bf(lo.w);
        a[4]=f2bf(hi.x); a[5]=f2bf(hi.y); a[6]=f2bf(hi.z); a[7]=f2bf(hi.w);
        c0 = __builtin_amdgcn_mfma_f32_16x16x32_bf16(a, bfr[ss][0], c0, 0, 0, 0);
        c1 = __builtin_amdgcn_mfma_f32_16x16x32_bf16(a, bfr[ss][1], c1, 0, 0, 0);
    }
    #pragma unroll
    for (int i = 0; i < 4; ++i) {
        const int orow = out_map[mapbase + m0 + quad * 4 + i];
        float* po = out + (long long)orow * COUT;
        atomicAdd(po + col,      c0[i]);
        atomicAdd(po + col + 16, c1[i]);
    }
}

extern "C" void kernel_launch(void* const* d_in, const int* in_sizes, int n_in,
                              void* d_out, int out_size, void* d_ws, size_t ws_size,
                              hipStream_t stream) {
    const float* feats   = (const float*)d_in[0];
    const float* weight  = (const float*)d_in[1];
    const int*   in_map  = (const int*)d_in[2];
    const int*   out_map = (const int*)d_in[3];
    float*       out     = (float*)d_out;

    if (ws_size >= WS_NEED1) {
        ushort*  feats_bf = (ushort*)d_ws;
        __half2* msgs     = (__half2*)((char*)d_ws + OFF_MSGS);
        int*     slists   = (int*)((char*)d_ws + OFF_SLISTS);
        int*     gcnt     = (int*)((char*)d_ws + OFF_GCNT);

        hipMemsetAsync(gcnt, 0, GCNT_BYTES, stream);
        feats_cvt_kernel<<<CVT_BLOCKS, 256, 0, stream>>>(feats, feats_bf);
        fill_kernel<<<FILL_BLOCKS, 1024, 0, stream>>>(out_map, slists, gcnt);
        msgs_kernel<<<dim3(BLK_PER_K, KOFF), 256, 0, stream>>>(
            feats_bf, weight, in_map, msgs);
        reduce_kernel<<<NS, 512, 0, stream>>>(
            (const unsigned int*)msgs, slists, gcnt, out);
    } else if (ws_size >= WS_NEED2) {
        __half2* accum    = (__half2*)d_ws;
        ushort*  feats_bf = (ushort*)((char*)d_ws + ACC_BYTES);
        prep4_kernel<<<CVT_BLOCKS + ZERO_BLOCKS, 256, 0, stream>>>(
            feats, feats_bf, (float4*)accum);
        spconv_pipe_kernel<<<dim3(BLK_PER_K, KOFF), 256, 0, stream>>>(
            feats_bf, weight, in_map, out_map, accum);
        h2_to_f32_kernel<<<(NOUT * 16 / 4) / 256, 256, 0, stream>>>(accum, out);
    } else {
        hipMemsetAsync(d_out, 0, (size_t)out_size * sizeof(float), stream);
        spconv_f32atomic_kernel<<<dim3((TILES + WPB - 1) / WPB, KOFF), 256, 0, stream>>>(
            feats, weight, in_map, out_map, out);
    }
}